// Round 2
// baseline (483.248 us; speedup 1.0000x reference)
//
#include <hip/hip_runtime.h>

// Depthwise conv1d, B=8 L=16384 C=512 K=31, SAME padding, fp32.
// out[b,l,c] = sum_k x[b, l+k-15, c] * w[k,c] + bias[c]
//
// R3. R2 post-mortem: conv dispatch is < 163 us (absent from top-5 which is
// topped by 1 GiB harness poison-fills at ~167 us); harness dur_us ~454
// includes ~334 us of those fills. Kernel est ~120 us vs ~95-108 us traffic
// roofline. So: pure traffic reduction this round.
//   - TL=128: halo read amplification (TL+30)/TL = 1.234x vs 1.53x at TL=64.
//     Reads 331 MB + writes 268 MB -> ~95 us at fill-rate 6.4 TB/s.
//   - Tail prefetch clamped to last needed row (TL+14): the PD lookahead rows
//     past the tile end become L1-hit repeats instead of wasted HBM lines.
//     (Safe: window rows >= TL+15 are never read by any output in the tile.)
//   - Nontemporal stores for out: 268 MB write-once stream no longer evicts
//     x halo from L2/L3.
//   - NWG=1024, swizzle (d&7)*128 + d>>3: XCD k owns batch b=k entirely ->
//     all halo reuse is intra-XCD L2.
// Register structure unchanged from R2 (constant in TL): xw[32] circular
// window + wk[31] + tmp[4] prefetch queue, ~160 VGPR -> 3 waves/SIMD.
// PD stays 4: R1 showed crossing the 170-VGPR/3-wave boundary -> scratch.

#define BB 8
#define LL 16384
#define CC 512
#define KK 31
#define PAD 15
#define TL 128
#define TILES_PER_B (LL / TL)      // 128
#define NWG (BB * TILES_PER_B)     // 1024
#define PD 4                       // prefetch queue depth (rows)
#define WIN 32                     // window slots, power of 2 > KK
#define LAST_ROW (TL + PAD - 1)    // last input row any output in tile needs

typedef float f32x2_t __attribute__((ext_vector_type(2)));

__global__ __launch_bounds__(256)
void depthconv1d_2680059592713_kernel(const float* __restrict__ x,
                                      const float* __restrict__ w,
                                      const float* __restrict__ bias,
                                      float* __restrict__ out) {
    const int c2 = threadIdx.x;                   // 0..255 -> float2 channel group
    const int d  = blockIdx.x;
    // XCD-aware swizzle (NWG % 8 == 0 -> bijective). XCD k gets tiles
    // [k*128, (k+1)*128) = all of batch b=k, contiguous in L.
    const int tile = (d & 7) * (NWG / 8) + (d >> 3);
    const int b    = tile >> 7;                   // / TILES_PER_B
    const int l0   = (tile & (TILES_PER_B - 1)) * TL;
    const int c    = c2 * 2;

    const float* xb = x + ((size_t)b * LL) * CC + c;

    // Bounds-checked row load; l0 + r is block-uniform -> scalar branch.
    auto loadrow = [&](int r) -> float2 {
        const int lr = l0 + r;
        if (lr >= 0 && lr < LL) {
            return *(const float2*)(xb + (size_t)lr * CC);
        }
        return make_float2(0.f, 0.f);
    };

    // Prologue: window rows -15..15 (row r lives in slot r & 31), prefetch
    // queue rows 16..19. Issue x loads before weight loads so the
    // long-latency streams start first.
    float2 xw[WIN];
#pragma unroll
    for (int r = -PAD; r <= PAD; ++r) {
        xw[r & (WIN - 1)] = loadrow(r);
    }

    float2 tmp[PD];
#pragma unroll
    for (int p = 0; p < PD; ++p) {
        tmp[p] = loadrow(PAD + 1 + p);            // rows 16..19
    }

    // Weights: w is (K, C, 1) flat k*C + c. 31 x float2 = 62 VGPRs; 62 KB
    // shared by all blocks -> L2.
    float2 wk[KK];
#pragma unroll
    for (int k = 0; k < KK; ++k) {
        wk[k] = *(const float2*)(w + k * CC + c);
    }
    const float2 bv = *(const float2*)(bias + c);

    float* ob = out + (((size_t)b * LL) + l0) * CC + c;

    // Steady state, step t = base + j:
    //   1. install row t+16 (loaded PD steps ago) into slot (t+16)&31,
    //      overwriting row t-16 (no longer needed),
    //   2. refill queue slot with row t+16+PD (clamped to LAST_ROW: repeats
    //      are L1 hits; clamped installs only touch rows >= TL+15 which no
    //      output reads),
    //   3. 31-tap FMA for output row t, 4. nontemporal store.
    // Slot indices depend only on j because base % WIN == 0.
#pragma unroll 1
    for (int base = 0; base < TL; base += WIN) {
#pragma unroll
        for (int j = 0; j < WIN; ++j) {
            xw[(j + PAD + 1) & (WIN - 1)] = tmp[j & (PD - 1)];
            const int pr = base + j + PAD + 1 + PD;
            tmp[j & (PD - 1)] = loadrow(pr < LAST_ROW ? pr : LAST_ROW);

            float2 acc = bv;
#pragma unroll
            for (int k = 0; k < KK; ++k) {
                const float2 xv = xw[(j + k - PAD) & (WIN - 1)];
                acc.x = fmaf(xv.x, wk[k].x, acc.x);
                acc.y = fmaf(xv.y, wk[k].y, acc.y);
            }

            __builtin_nontemporal_store(*(const f32x2_t*)&acc,
                                        (f32x2_t*)(ob + (size_t)(base + j) * CC));
        }
    }
}

extern "C" void kernel_launch(void* const* d_in, const int* in_sizes, int n_in,
                              void* d_out, int out_size, void* d_ws, size_t ws_size,
                              hipStream_t stream) {
    const float* x    = (const float*)d_in[0];
    const float* w    = (const float*)d_in[1];
    const float* bias = (const float*)d_in[2];
    float* out        = (float*)d_out;

    hipLaunchKernelGGL(depthconv1d_2680059592713_kernel,
                       dim3(NWG), dim3(256), 0, stream,
                       x, w, bias, out);
}